// Round 6
// baseline (782.031 us; speedup 1.0000x reference)
//
#include <hip/hip_runtime.h>
#include <hip/hip_bf16.h>
#include <stdint.h>

typedef __attribute__((ext_vector_type(8)))  __bf16 bf16x8;
typedef __attribute__((ext_vector_type(4)))  float  f32x4;
typedef __attribute__((ext_vector_type(16))) float  f32x16;

#define IN_F   4096
#define OUT_F  4096
#define M_ROWS 16384   // 8 * 2048

static __device__ __forceinline__ unsigned short f2bf(float f) {
    unsigned int u = __float_as_uint(f);
    u += 0x7FFFu + ((u >> 16) & 1u);   // round-to-nearest-even
    return (unsigned short)(u >> 16);
}

// ---------------------------------------------------------------------------
// Kernel 1: fused prep.
//   blocks [0, WBLK): build full weight (OUT_F x IN_F) bf16 into wb
//   blocks [WBLK, NBLK): convert x fp32 -> bf16 into xbuf
// ---------------------------------------------------------------------------
#define PREP_WBLK 1366
#define PREP_NBLK 4096

__global__ __launch_bounds__(256) void prep_kernel(
    const float* __restrict__ weight, const float* __restrict__ leafs,
    const float* __restrict__ x,
    unsigned short* __restrict__ wb, unsigned short* __restrict__ xbuf)
{
    const int t = threadIdx.x;
    if (blockIdx.x < PREP_WBLK) {
        __shared__ float s[4][8][8];
        {
            const int o = t >> 6, a = (t >> 3) & 7, b = t & 7;
            float acc = 0.f;
            #pragma unroll
            for (int r = 0; r < 8; ++r)
                acc += leafs[o * 512 + r * 64 + a * 8 + b];
            s[o][a][b] = acc;
        }
        __syncthreads();

        const int total = (OUT_F * IN_F) / 8;
        for (int idx = blockIdx.x * 256 + t; idx < total; idx += PREP_WBLK * 256) {
            const int n  = idx >> 9;
            const int kg = idx & 511;
            const int n0 = n >> 9, n1 = (n >> 6) & 7, n2 = (n >> 3) & 7, n3 = n & 7;
            const int k0 = kg >> 6, k1 = (kg >> 3) & 7, k2 = kg & 7;
            const float p = s[0][k0][n0] * s[1][k1][n1] * s[2][k2][n2];
            const float4* wp = (const float4*)(weight + (size_t)n * IN_F + kg * 8);
            const float4 w0 = wp[0], w1 = wp[1];
            const float wv[8] = {w0.x, w0.y, w0.z, w0.w, w1.x, w1.y, w1.z, w1.w};
            unsigned int pk[4];
            #pragma unroll
            for (int j = 0; j < 4; ++j) {
                unsigned int lo = f2bf(wv[2*j]   + p * s[3][2*j]  [n3]);
                unsigned int hi = f2bf(wv[2*j+1] + p * s[3][2*j+1][n3]);
                pk[j] = lo | (hi << 16);
            }
            *reinterpret_cast<uint4*>(wb + (size_t)n * IN_F + kg * 8) =
                make_uint4(pk[0], pk[1], pk[2], pk[3]);
        }
    } else {
        const long long n8 = (long long)M_ROWS * IN_F / 8;
        const int xblocks = PREP_NBLK - PREP_WBLK;
        for (long long idx = (long long)(blockIdx.x - PREP_WBLK) * 256 + t;
             idx < n8; idx += (long long)xblocks * 256) {
            const float4* xp = (const float4*)(x + idx * 8);
            const float4 a = xp[0], b = xp[1];
            const float v[8] = {a.x, a.y, a.z, a.w, b.x, b.y, b.z, b.w};
            unsigned int pk[4];
            #pragma unroll
            for (int j = 0; j < 4; ++j)
                pk[j] = (unsigned int)f2bf(v[2*j]) | ((unsigned int)f2bf(v[2*j+1]) << 16);
            *reinterpret_cast<uint4*>(xbuf + idx * 8) =
                make_uint4(pk[0], pk[1], pk[2], pk[3]);
        }
    }
}

// ---------------------------------------------------------------------------
// Kernel 2: 256x256 GEMM, mfma_f32_32x32x16_bf16, k-pair-major LDS layout.
//
// LDS (128 KiB, double-buffered): buf p at p*65536.
//   A panel:  [4 k-pair sp][256 rows][32 B]  at +0      (32 KB)
//   B panel:  same                           at +32768  (32 KB)
// Element (row, k): sp = (k % 64) / 16, half = (k / 8) & 1 ->
//   byte = sp*8192 + row*32 + half*16.  NO swizzle needed: every
//   ds_read_b128 (fixed fm/fn, ks) covers a contiguous 1024-B block =
//   8 full 128-B lines, 8 lanes each (conflict-free by construction).
//
// Staging: chunk c (16 B) at byte c*16; c = sp*512 + row*2 + half ->
//   thread t stages chunks t + i*512 (i=0..3): row (t>>1)&255, half t&1,
//   sp = i. Linear LDS dest (global_load_lds rule), per-lane global src.
//
// Loop (catalog T3-minimum 2-phase): per K-tile
//   { STAGE(next -> buf^1); compiler-scheduled 24 ds_read + 32 MFMA
//     (hipcc auto-ladders lgkmcnt); setprio around; __syncthreads() }.
// __syncthreads' vmcnt(0) is covered by the full-tile distance since GLLs
// issue at tile start.
// ---------------------------------------------------------------------------
#define BK 64
#define NT 64

#define GLL(src, dst) __builtin_amdgcn_global_load_lds( \
    (const __attribute__((address_space(1))) void*)(src), \
    (__attribute__((address_space(3))) void*)(dst), 16, 0, 0)

#define STAGE(P, KO) do { _Pragma("unroll") \
    for (int i_ = 0; i_ < 4; ++i_) { \
        GLL(srcA + (KO) + i_ * 16, ldsb + (P)*65536 + t*16 + i_*8192); \
        GLL(srcB + (KO) + i_ * 16, ldsb + (P)*65536 + 32768 + t*16 + i_*8192); \
    } } while (0)

__global__ __launch_bounds__(512, 2) void gemm32k_kernel(
    const unsigned short* __restrict__ xb,   // bf16 x [M_ROWS][IN_F]
    const unsigned short* __restrict__ wb,   // bf16 W [OUT_F][IN_F]
    const float* __restrict__ bias,
    float* __restrict__ out)
{
    __shared__ unsigned short lds_us[65536];   // 128 KiB
    char* const ldsb = (char*)lds_us;

    const int t    = threadIdx.x;
    const int wave = t >> 6;
    const int lane = t & 63;
    const int ln31 = lane & 31;
    const int lhi  = lane >> 5;          // 0..1 (k-half within 16-k step)
    const int wr   = wave >> 2;          // 0..1  (M half)
    const int wcn  = wave & 3;           // 0..3  (N quarter)

    // XCD-chunked swizzle; bn-major within chunk keeps the A slice L2-hot.
    const int bid  = blockIdx.x;
    const int swzb = (bid & 7) * 128 + (bid >> 3);
    const int bm   = (swzb >> 4) * 256;   // 64 M-tiles
    const int bn   = (swzb & 15) * 256;   // 16 N-tiles

    // staging sources (elems); KO (k-tile offset in elems) added per stage
    const unsigned short* srcA =
        xb + (size_t)(bm + ((t >> 1) & 255)) * IN_F + (t & 1) * 8;
    const unsigned short* srcB =
        wb + (size_t)(bn + ((t >> 1) & 255)) * IN_F + (t & 1) * 8;

    // per-lane read bases within a buffer (byte offsets)
    const int aOff = (wr * 128 + ln31) * 32 + lhi * 16;            // A panel
    const int bOff = 32768 + (wcn * 64 + ln31) * 32 + lhi * 16;    // B panel

    f32x16 acc[4][2] = {};

    // prologue: stage tile 0 into buf 0
    STAGE(0, 0);
    __syncthreads();

    #pragma unroll 1
    for (int tt = 0; tt < NT; ++tt) {
        const int p = tt & 1;
        if (tt + 1 < NT) STAGE(p ^ 1, (tt + 1) * BK);

        const char* pan = ldsb + p * 65536;
        __builtin_amdgcn_s_setprio(1);
        #pragma unroll
        for (int ks = 0; ks < 4; ++ks) {
            bf16x8 a[4], b[2];
            #pragma unroll
            for (int m = 0; m < 4; ++m)
                a[m] = *(const bf16x8*)(pan + ks * 8192 + aOff + m * 1024);
            #pragma unroll
            for (int n = 0; n < 2; ++n)
                b[n] = *(const bf16x8*)(pan + ks * 8192 + bOff + n * 1024);
            #pragma unroll
            for (int m = 0; m < 4; ++m)
                #pragma unroll
                for (int n = 0; n < 2; ++n)
                    acc[m][n] = __builtin_amdgcn_mfma_f32_32x32x16_bf16(
                        a[m], b[n], acc[m][n], 0, 0, 0);
        }
        __builtin_amdgcn_s_setprio(0);
        __syncthreads();
    }

    // ---- epilogue: C/D col = lane&31, row = (reg&3) + 8*(reg>>2) + 4*lhi ----
    #pragma unroll
    for (int fn = 0; fn < 2; ++fn) {
        const int col = bn + wcn * 64 + fn * 32 + ln31;
        const float bv = bias[col];
        #pragma unroll
        for (int fm = 0; fm < 4; ++fm) {
            const int rb = bm + wr * 128 + fm * 32 + 4 * lhi;
            #pragma unroll
            for (int reg = 0; reg < 16; ++reg) {
                const int row = rb + (reg & 3) + 8 * (reg >> 2);
                out[(size_t)row * OUT_F + col] = acc[fm][fn][reg] + bv;
            }
        }
    }
}

// ---------------------------------------------------------------------------
// Fallback GEMM (round-1 structure) for small workspace.
// ---------------------------------------------------------------------------
#define FBM 128
#define FBN 128
#define FBK 32

__global__ __launch_bounds__(256) void gemm_fb_kernel(
    const float* __restrict__ xf,
    const unsigned short* __restrict__ wb,
    const float* __restrict__ bias,
    float* __restrict__ out)
{
    __shared__ unsigned short As[FBM * FBK];
    __shared__ unsigned short Bs[FBN * FBK];

    const int t    = threadIdx.x;
    const int wave = t >> 6;
    const int lane = t & 63;
    const int lr   = lane & 15;
    const int kq   = lane >> 4;
    const int wr   = wave >> 1;
    const int wc   = wave & 1;

    const int bm = blockIdx.x * FBM;
    const int bn = blockIdx.y * FBN;
    const int srow = t >> 2;
    const int scol = (t & 3) * 8;

    f32x4 acc[4][4] = {};

    for (int kt = 0; kt < IN_F; kt += FBK) {
        #pragma unroll
        for (int g = 0; g < 2; ++g) {
            const int row = srow + g * 64;
            const float4* xp = (const float4*)(xf + (size_t)(bm + row) * IN_F + kt + scol);
            const float4 a0 = xp[0], a1 = xp[1];
            const float v[8] = {a0.x, a0.y, a0.z, a0.w, a1.x, a1.y, a1.z, a1.w};
            unsigned int pk[4];
            #pragma unroll
            for (int j = 0; j < 4; ++j)
                pk[j] = (unsigned int)f2bf(v[2*j]) | ((unsigned int)f2bf(v[2*j+1]) << 16);
            *reinterpret_cast<uint4*>(&As[row * FBK + scol]) =
                make_uint4(pk[0], pk[1], pk[2], pk[3]);
        }
        {
            const unsigned short* gb0 = wb + (size_t)(bn + srow) * IN_F + kt + scol;
            const unsigned short* gb1 = gb0 + (size_t)64 * IN_F;
            GLL(gb0, Bs + srow * FBK + scol);
            GLL(gb1, Bs + (64 + srow) * FBK + scol);
        }
        __syncthreads();

        bf16x8 af[4], bfr[4];
        #pragma unroll
        for (int m = 0; m < 4; ++m)
            af[m] = *reinterpret_cast<const bf16x8*>(As + (wr * 64 + m * 16 + lr) * FBK + kq * 8);
        #pragma unroll
        for (int n = 0; n < 4; ++n)
            bfr[n] = *reinterpret_cast<const bf16x8*>(Bs + (wc * 64 + n * 16 + lr) * FBK + kq * 8);

        #pragma unroll
        for (int m = 0; m < 4; ++m)
            #pragma unroll
            for (int n = 0; n < 4; ++n)
                acc[m][n] = __builtin_amdgcn_mfma_f32_16x16x32_bf16(af[m], bfr[n], acc[m][n], 0, 0, 0);

        __syncthreads();
    }

    const int crow0 = kq * 4;
    #pragma unroll
    for (int n = 0; n < 4; ++n) {
        const int col = bn + wc * 64 + n * 16 + lr;
        const float bv = bias[col];
        #pragma unroll
        for (int m = 0; m < 4; ++m) {
            const int rowb = bm + wr * 64 + m * 16 + crow0;
            #pragma unroll
            for (int j = 0; j < 4; ++j)
                out[(size_t)(rowb + j) * OUT_F + col] = acc[m][n][j] + bv;
        }
    }
}

// ---------------------------------------------------------------------------
extern "C" void kernel_launch(void* const* d_in, const int* in_sizes, int n_in,
                              void* d_out, int out_size, void* d_ws, size_t ws_size,
                              hipStream_t stream) {
    const float* x      = (const float*)d_in[0];
    const float* weight = (const float*)d_in[1];
    const float* bias   = (const float*)d_in[2];
    const float* leafs  = (const float*)d_in[3];
    float* out = (float*)d_out;

    unsigned short* wb = (unsigned short*)d_ws;
    unsigned short* xbuf = (unsigned short*)((char*)d_ws +
                           (size_t)OUT_F * IN_F * sizeof(unsigned short));

    const size_t need_full = (size_t)OUT_F * IN_F * 2 + (size_t)M_ROWS * IN_F * 2;
    const bool full = ws_size >= need_full;

    if (full) {
        prep_kernel<<<dim3(PREP_NBLK), dim3(256), 0, stream>>>(
            weight, leafs, x, wb, xbuf);
        gemm32k_kernel<<<dim3((M_ROWS / 256) * (OUT_F / 256)), dim3(512), 0, stream>>>(
            xbuf, wb, bias, out);
    } else {
        prep_kernel<<<dim3(PREP_WBLK), dim3(256), 0, stream>>>(
            weight, leafs, x, wb, xbuf);
        gemm_fb_kernel<<<dim3(M_ROWS / FBM, OUT_F / FBN), dim3(256), 0, stream>>>(
            x, wb, bias, out);
    }
}

// Round 7
// 587.650 us; speedup vs baseline: 1.3308x; 1.3308x over previous
//
#include <hip/hip_runtime.h>
#include <hip/hip_bf16.h>
#include <stdint.h>

typedef __attribute__((ext_vector_type(8))) __bf16 bf16x8;
typedef __attribute__((ext_vector_type(4))) float f32x4;

#define IN_F   4096
#define OUT_F  4096
#define M_ROWS 16384   // 8 * 2048

static __device__ __forceinline__ unsigned short f2bf(float f) {
    unsigned int u = __float_as_uint(f);
    u += 0x7FFFu + ((u >> 16) & 1u);   // round-to-nearest-even
    return (unsigned short)(u >> 16);
}

// ---------------------------------------------------------------------------
// Kernel 1: fused prep.
//   blocks [0, WBLK): build full weight (OUT_F x IN_F) bf16 into wb
//   blocks [WBLK, NBLK): convert x fp32 -> bf16 into xbuf
// ---------------------------------------------------------------------------
#define PREP_WBLK 1366
#define PREP_NBLK 4096

__global__ __launch_bounds__(256) void prep_kernel(
    const float* __restrict__ weight, const float* __restrict__ leafs,
    const float* __restrict__ x,
    unsigned short* __restrict__ wb, unsigned short* __restrict__ xbuf)
{
    const int t = threadIdx.x;
    if (blockIdx.x < PREP_WBLK) {
        __shared__ float s[4][8][8];
        {
            const int o = t >> 6, a = (t >> 3) & 7, b = t & 7;
            float acc = 0.f;
            #pragma unroll
            for (int r = 0; r < 8; ++r)
                acc += leafs[o * 512 + r * 64 + a * 8 + b];
            s[o][a][b] = acc;
        }
        __syncthreads();

        const int total = (OUT_F * IN_F) / 8;
        for (int idx = blockIdx.x * 256 + t; idx < total; idx += PREP_WBLK * 256) {
            const int n  = idx >> 9;
            const int kg = idx & 511;
            const int n0 = n >> 9, n1 = (n >> 6) & 7, n2 = (n >> 3) & 7, n3 = n & 7;
            const int k0 = kg >> 6, k1 = (kg >> 3) & 7, k2 = kg & 7;
            const float p = s[0][k0][n0] * s[1][k1][n1] * s[2][k2][n2];
            const float4* wp = (const float4*)(weight + (size_t)n * IN_F + kg * 8);
            const float4 w0 = wp[0], w1 = wp[1];
            const float wv[8] = {w0.x, w0.y, w0.z, w0.w, w1.x, w1.y, w1.z, w1.w};
            unsigned int pk[4];
            #pragma unroll
            for (int j = 0; j < 4; ++j) {
                unsigned int lo = f2bf(wv[2*j]   + p * s[3][2*j]  [n3]);
                unsigned int hi = f2bf(wv[2*j+1] + p * s[3][2*j+1][n3]);
                pk[j] = lo | (hi << 16);
            }
            *reinterpret_cast<uint4*>(wb + (size_t)n * IN_F + kg * 8) =
                make_uint4(pk[0], pk[1], pk[2], pk[3]);
        }
    } else {
        const long long n8 = (long long)M_ROWS * IN_F / 8;
        const int xblocks = PREP_NBLK - PREP_WBLK;
        for (long long idx = (long long)(blockIdx.x - PREP_WBLK) * 256 + t;
             idx < n8; idx += (long long)xblocks * 256) {
            const float4* xp = (const float4*)(x + idx * 8);
            const float4 a = xp[0], b = xp[1];
            const float v[8] = {a.x, a.y, a.z, a.w, b.x, b.y, b.z, b.w};
            unsigned int pk[4];
            #pragma unroll
            for (int j = 0; j < 4; ++j)
                pk[j] = (unsigned int)f2bf(v[2*j]) | ((unsigned int)f2bf(v[2*j+1]) << 16);
            *reinterpret_cast<uint4*>(xbuf + idx * 8) =
                make_uint4(pk[0], pk[1], pk[2], pk[3]);
        }
    }
}

// ---------------------------------------------------------------------------
// Kernel 2: 256x256 GEMM, 16x16x32 MFMA, R3-proven LDS layout (0 conflicts),
// TWO barriers per K-tile (one per K=32 half) for cross-wave pipe overlap.
//
// LDS: A panels [2buf][2kk][256 rows][64 B] at 0; B same at 65536. 128 KiB.
// Element (row, col): byte row*64 + ((col*2) ^ ((row&6)<<3))  [R3: 0 confl].
// Staged linearly by global_load_lds from inverse-swizzled global sources.
//
// Per half (buf P, kk): { stage 4 GLL (next tile, same kk); issue 12 ds_reads
//   (aG1 m0-3, bG n0-3, aG2 m4-7); lgkmcnt(4) -> 16 MFMA (aG2 drains under);
//   lgkmcnt(0) -> 16 MFMA; vmcnt(4); barrier }.
// FIFO: steady-state vmcnt(4) waits GLLs issued 2 halves (~2300 cyc) earlier;
// at barrier release all waves' GLLs for the next half's panels have landed.
// Panel overwrite separated from its last reader by >= 2 barriers.
// ---------------------------------------------------------------------------
#define BK 64
#define NT 64

#define PANEL_A(b,kk) (ldsb + ((b)*2+(kk))*16384)
#define PANEL_B(b,kk) (ldsb + 65536 + ((b)*2+(kk))*16384)

#define GLL(src, dst) __builtin_amdgcn_global_load_lds( \
    (const __attribute__((address_space(1))) void*)(src), \
    (__attribute__((address_space(3))) void*)(dst), 16, 0, 0)

#define STAGE_A(b, kk, ko) do { \
    GLL(sA1 + (ko) + (kk)*32,          PANEL_A(b,kk) + d1); \
    GLL(sA1 + 524288 + (ko) + (kk)*32, PANEL_A(b,kk) + d1 + 8192); } while(0)
#define STAGE_B(b, kk, ko) do { \
    GLL(sB1 + (ko) + (kk)*32,          PANEL_B(b,kk) + d1); \
    GLL(sB1 + 524288 + (ko) + (kk)*32, PANEL_B(b,kk) + d1 + 8192); } while(0)

#define SB0  __builtin_amdgcn_sched_barrier(0)
#define BAR  __builtin_amdgcn_s_barrier()
#define PRI1 __builtin_amdgcn_s_setprio(1)
#define PRI0 __builtin_amdgcn_s_setprio(0)
#define WLG4 asm volatile("s_waitcnt lgkmcnt(4)" ::: "memory")
#define WLG0 asm volatile("s_waitcnt lgkmcnt(0)" ::: "memory")
#define WVM4 asm volatile("s_waitcnt vmcnt(4)" ::: "memory")
#define WVM0 asm volatile("s_waitcnt vmcnt(0)" ::: "memory")

// One K=32 half: panel (P, KK); optionally stage (P^1, KK) at ko.
#define HALF(P, KK, KO, PF) do { \
    if (PF) { STAGE_A((P)^1, KK, KO); STAGE_B((P)^1, KK, KO); } \
    _Pragma("unroll") \
    for (int i_ = 0; i_ < 4; ++i_) \
        aG1[i_] = *(const bf16x8*)(aB + (P)*32768 + (KK)*16384 + i_*1024); \
    _Pragma("unroll") \
    for (int i_ = 0; i_ < 4; ++i_) \
        bG[i_]  = *(const bf16x8*)(bB + (P)*32768 + (KK)*16384 + i_*1024); \
    _Pragma("unroll") \
    for (int i_ = 0; i_ < 4; ++i_) \
        aG2[i_] = *(const bf16x8*)(aB + (P)*32768 + (KK)*16384 + (4+i_)*1024); \
    SB0; WLG4; SB0; \
    PRI1; \
    _Pragma("unroll") \
    for (int m_ = 0; m_ < 4; ++m_) { _Pragma("unroll") \
    for (int n_ = 0; n_ < 4; ++n_) \
        acc[m_][n_] = __builtin_amdgcn_mfma_f32_16x16x32_bf16( \
            aG1[m_], bG[n_], acc[m_][n_], 0, 0, 0); } \
    PRI0; SB0; WLG0; SB0; \
    PRI1; \
    _Pragma("unroll") \
    for (int m_ = 0; m_ < 4; ++m_) { _Pragma("unroll") \
    for (int n_ = 0; n_ < 4; ++n_) \
        acc[4+m_][n_] = __builtin_amdgcn_mfma_f32_16x16x32_bf16( \
            aG2[m_], bG[n_], acc[4+m_][n_], 0, 0, 0); } \
    PRI0; SB0; \
    if (PF) { WVM4; } else { WVM0; } \
    BAR; SB0; \
} while (0)

__global__ __launch_bounds__(512, 2) void gemm2b_kernel(
    const unsigned short* __restrict__ xb,   // bf16 x [M_ROWS][IN_F]
    const unsigned short* __restrict__ wb,   // bf16 W [OUT_F][IN_F]
    const float* __restrict__ bias,
    float* __restrict__ out)
{
    __shared__ unsigned short lds_us[65536];   // 128 KiB
    char* const ldsb = (char*)lds_us;

    const int t    = threadIdx.x;
    const int wave = t >> 6;
    const int lane = t & 63;
    const int lr   = lane & 15;
    const int kq   = lane >> 4;
    const int wr   = wave >> 2;      // 0..1  (M)
    const int wcn  = wave & 3;       // 0..3  (N)
    const int sx   = (lr & 6) << 3;

    // XCD-chunked swizzle; bn-major within chunk keeps the A slice L2-hot.
    const int bid  = blockIdx.x;
    const int swzb = (bid & 7) * 128 + (bid >> 3);
    const int bm   = (swzb >> 4) * 256;   // 64 M-tiles
    const int bn   = (swzb & 15) * 256;   // 16 N-tiles

    // staging: thread t covers 16B chunks t and t+512 of each panel (linear)
    const int c1 = t;
    const int r1 = c1 >> 2;                               // panel row (0..127)
    const int q1 = ((c1 & 3) * 16) ^ ((r1 & 6) << 3);     // inv-swizzled src byte
    const unsigned short* sA1 = xb + (size_t)(bm + r1) * IN_F + (q1 >> 1);
    const unsigned short* sB1 = wb + (size_t)(bn + r1) * IN_F + (q1 >> 1);
    const int d1 = c1 * 16;                               // lds dest (linear)
    // chunk 2: row r1+128 (same swizzle since (r+128)&6 == r&6), global
    // +128 rows = +524288 elements, lds dest d1 + 8192.

    // per-lane read bases (swizzled); fragment offsets are immediates
    const char* aB = ldsb + (wr * 128 + lr) * 64 + ((kq * 16) ^ sx);
    const char* bB = ldsb + 65536 + (wcn * 64 + lr) * 64 + ((kq * 16) ^ sx);

    f32x4 acc[8][4] = {};
    bf16x8 aG1[4], aG2[4], bG[4];

    // prologue: stage tile 0 (k0 then k1), drain k0, sync.
    // Entering tile 0 half 0: outstanding = 4 (k1 panels) -> matches steady
    // state (at each half start, the other-kk panels of this tile in flight).
    STAGE_A(0, 0, 0); STAGE_B(0, 0, 0); STAGE_A(0, 1, 0); STAGE_B(0, 1, 0);
    WVM4; BAR; SB0;

    #pragma unroll 1
    for (int tt = 0; tt < NT - 1; ++tt) {
        const int p  = tt & 1;
        const int ko = (tt + 1) * BK;
        HALF(p, 0, ko, true);
        HALF(p, 1, ko, true);
    }
    HALF(1, 0, 0, false);   // tile 63 (buf 1), no staging
    HALF(1, 1, 0, false);

    // ---- epilogue: C/D layout col=lr, row=kq*4+j ----
    #pragma unroll
    for (int n = 0; n < 4; ++n) {
        const int col = bn + wcn * 64 + n * 16 + lr;
        const float bv = bias[col];
        #pragma unroll
        for (int m = 0; m < 8; ++m) {
            const size_t rb = (size_t)(bm + wr * 128 + m * 16 + kq * 4) * OUT_F + col;
            #pragma unroll
            for (int j = 0; j < 4; ++j)
                out[rb + (size_t)j * OUT_F] = acc[m][n][j] + bv;
        }
    }
}

// ---------------------------------------------------------------------------
// Fallback GEMM (round-1 structure) for small workspace.
// ---------------------------------------------------------------------------
#define FBM 128
#define FBN 128
#define FBK 32

__global__ __launch_bounds__(256) void gemm_fb_kernel(
    const float* __restrict__ xf,
    const unsigned short* __restrict__ wb,
    const float* __restrict__ bias,
    float* __restrict__ out)
{
    __shared__ unsigned short As[FBM * FBK];
    __shared__ unsigned short Bs[FBN * FBK];

    const int t    = threadIdx.x;
    const int wave = t >> 6;
    const int lane = t & 63;
    const int lr   = lane & 15;
    const int kq   = lane >> 4;
    const int wr   = wave >> 1;
    const int wc   = wave & 1;

    const int bm = blockIdx.x * FBM;
    const int bn = blockIdx.y * FBN;
    const int srow = t >> 2;
    const int scol = (t & 3) * 8;

    f32x4 acc[4][4] = {};

    for (int kt = 0; kt < IN_F; kt += FBK) {
        #pragma unroll
        for (int g = 0; g < 2; ++g) {
            const int row = srow + g * 64;
            const float4* xp = (const float4*)(xf + (size_t)(bm + row) * IN_F + kt + scol);
            const float4 a0 = xp[0], a1 = xp[1];
            const float v[8] = {a0.x, a0.y, a0.z, a0.w, a1.x, a1.y, a1.z, a1.w};
            unsigned int pk[4];
            #pragma unroll
            for (int j = 0; j < 4; ++j)
                pk[j] = (unsigned int)f2bf(v[2*j]) | ((unsigned int)f2bf(v[2*j+1]) << 16);
            *reinterpret_cast<uint4*>(&As[row * FBK + scol]) =
                make_uint4(pk[0], pk[1], pk[2], pk[3]);
        }
        {
            const unsigned short* gb0 = wb + (size_t)(bn + srow) * IN_F + kt + scol;
            const unsigned short* gb1 = gb0 + (size_t)64 * IN_F;
            GLL(gb0, Bs + srow * FBK + scol);
            GLL(gb1, Bs + (64 + srow) * FBK + scol);
        }
        __syncthreads();

        bf16x8 af[4], bfr[4];
        #pragma unroll
        for (int m = 0; m < 4; ++m)
            af[m] = *reinterpret_cast<const bf16x8*>(As + (wr * 64 + m * 16 + lr) * FBK + kq * 8);
        #pragma unroll
        for (int n = 0; n < 4; ++n)
            bfr[n] = *reinterpret_cast<const bf16x8*>(Bs + (wc * 64 + n * 16 + lr) * FBK + kq * 8);

        #pragma unroll
        for (int m = 0; m < 4; ++m)
            #pragma unroll
            for (int n = 0; n < 4; ++n)
                acc[m][n] = __builtin_amdgcn_mfma_f32_16x16x32_bf16(af[m], bfr[n], acc[m][n], 0, 0, 0);

        __syncthreads();
    }

    const int crow0 = kq * 4;
    #pragma unroll
    for (int n = 0; n < 4; ++n) {
        const int col = bn + wc * 64 + n * 16 + lr;
        const float bv = bias[col];
        #pragma unroll
        for (int m = 0; m < 4; ++m) {
            const int rowb = bm + wr * 64 + m * 16 + crow0;
            #pragma unroll
            for (int j = 0; j < 4; ++j)
                out[(size_t)(rowb + j) * OUT_F + col] = acc[m][n][j] + bv;
        }
    }
}

// ---------------------------------------------------------------------------
extern "C" void kernel_launch(void* const* d_in, const int* in_sizes, int n_in,
                              void* d_out, int out_size, void* d_ws, size_t ws_size,
                              hipStream_t stream) {
    const float* x      = (const float*)d_in[0];
    const float* weight = (const float*)d_in[1];
    const float* bias   = (const float*)d_in[2];
    const float* leafs  = (const float*)d_in[3];
    float* out = (float*)d_out;

    unsigned short* wb = (unsigned short*)d_ws;
    unsigned short* xbuf = (unsigned short*)((char*)d_ws +
                           (size_t)OUT_F * IN_F * sizeof(unsigned short));

    const size_t need_full = (size_t)OUT_F * IN_F * 2 + (size_t)M_ROWS * IN_F * 2;
    const bool full = ws_size >= need_full;

    if (full) {
        prep_kernel<<<dim3(PREP_NBLK), dim3(256), 0, stream>>>(
            weight, leafs, x, wb, xbuf);
        gemm2b_kernel<<<dim3((M_ROWS / 256) * (OUT_F / 256)), dim3(512), 0, stream>>>(
            xbuf, wb, bias, out);
    } else {
        prep_kernel<<<dim3(PREP_WBLK), dim3(256), 0, stream>>>(
            weight, leafs, x, wb, xbuf);
        gemm_fb_kernel<<<dim3(M_ROWS / FBM, OUT_F / FBN), dim3(256), 0, stream>>>(
            x, wb, bias, out);
    }
}